// Round 2
// baseline (781.408 us; speedup 1.0000x reference)
//
#include <hip/hip_runtime.h>

// ---------------------------------------------------------------------------
// GNN_6305011991202: 2-layer GraphSAGE (mean aggr) + linear head.
// ALL float tensors are fp32 (reference dtype); edge_index delivered as int32.
//   h1 = relu(mean1 @ W1_l^T + b1_l + x  @ W1_r^T)
//   h2 = relu(mean2 @ W2_l^T + b2_l + h1 @ W2_r^T)
//   out = h2 @ W3^T + b3          (out: [50000, 64] fp32)
// GEMMs run on bf16 MFMA (weights pre-converted, fp32 accumulate); scatter
// aggregation uses fp32 atomics into a workspace accumulator.
// ---------------------------------------------------------------------------

typedef __bf16 bf16x8 __attribute__((ext_vector_type(8)));
typedef float floatx4 __attribute__((ext_vector_type(4)));

__device__ __forceinline__ float bf2f(unsigned short u) {
    union { unsigned int i; float f; } c;
    c.i = ((unsigned int)u) << 16;
    return c.f;
}
__device__ __forceinline__ unsigned short f2bf(float f) {
    union { float f; unsigned int i; } c;
    c.f = f;
    unsigned int i = c.i;
    unsigned int r = (i + 0x7fffu + ((i >> 16) & 1u)) >> 16;  // RNE
    return (unsigned short)r;
}

// ---------------------------------------------------------------------------
__global__ __launch_bounds__(256) void zero_kernel(float* __restrict__ p, int n4) {
    int i = blockIdx.x * 256 + threadIdx.x;
    if (i < n4) ((float4*)p)[i] = make_float4(0.f, 0.f, 0.f, 0.f);
}

// fp32 -> bf16 elementwise convert (weights), 4 elems/thread
__global__ __launch_bounds__(256) void cvt_kernel(const float* __restrict__ in,
                                                  unsigned short* __restrict__ out,
                                                  int n4) {
    int i = blockIdx.x * 256 + threadIdx.x;
    if (i >= n4) return;
    float4 v = ((const float4*)in)[i];
    ushort4 o;
    o.x = f2bf(v.x); o.y = f2bf(v.y); o.z = f2bf(v.z); o.w = f2bf(v.w);
    ((ushort4*)out)[i] = o;
}

// ---------------------------------------------------------------------------
// scatter-add: agg[dst[e]][:] += feat[src[e]][:]; 128 threads/edge.
template <bool FEAT_F32, bool COUNT>
__global__ __launch_bounds__(256) void scatter_add_kernel(
    const void* __restrict__ feat,            // [N,128] f32 or bf16
    const int* __restrict__ src, const int* __restrict__ dst,
    float* __restrict__ agg,                  // [N,128] f32
    float* __restrict__ deg,                  // [N] f32 (only if COUNT)
    int E)
{
    int idx = blockIdx.x * 256 + threadIdx.x;
    int e = idx >> 7;
    if (e >= E) return;
    int f = idx & 127;
    int s = src[e];
    int d = dst[e];
    float v;
    if (FEAT_F32) v = ((const float*)feat)[(size_t)s * 128 + f];
    else          v = bf2f(((const unsigned short*)feat)[(size_t)s * 128 + f]);
    atomicAdd(agg + (size_t)d * 128 + f, v);
    if (COUNT && f == 0) atomicAdd(deg + d, 1.0f);
}

// ---------------------------------------------------------------------------
// mean[n][f] = bf16(agg[n][f] / max(deg[n],1));  one thread per 4 features
__global__ __launch_bounds__(256) void finalize_mean_kernel(
    const float* __restrict__ agg, const float* __restrict__ deg,
    unsigned short* __restrict__ mean, int N)
{
    int idx = blockIdx.x * 256 + threadIdx.x;
    if (idx >= N * 32) return;
    int n = idx >> 5;
    float4 a = ((const float4*)agg)[idx];
    float inv = 1.0f / fmaxf(deg[n], 1.0f);
    ushort4 o;
    o.x = f2bf(a.x * inv);
    o.y = f2bf(a.y * inv);
    o.z = f2bf(a.z * inv);
    o.w = f2bf(a.w * inv);
    ((ushort4*)mean)[idx] = o;
}

// ---------------------------------------------------------------------------
// Fused SAGE GEMM: out = [relu]( inA @ Wl^T + bias [+ inS @ Wr^T] )
// inA: [M,128] bf16. inS: [M,128] fp32 (SELF_F32) or bf16. Wl/Wr: bf16
// [NT*16,128] (pre-converted, PyTorch [out_f,in_f] layout -> rows are B^T
// rows). bias fp32. out: bf16 (OUT_BF16) or fp32, [M, NT*16].
// One wave per 16 output rows; mfma_f32_16x16x32_bf16, fragment mapping
// (HW-verified m89/m91): A/B elem [m = lane&15][k = (lane>>4)*8 + j];
// C/D elem [row = (lane>>4)*4 + reg][col = lane&15].
template <int NT, bool DUAL, bool SELF_F32, bool RELU, bool OUT_BF16>
__global__ __launch_bounds__(256) void sage_gemm_kernel(
    const unsigned short* __restrict__ inA,
    const void* __restrict__ inS,
    const unsigned short* __restrict__ Wl,
    const unsigned short* __restrict__ Wr,
    const float* __restrict__ bias,
    void* __restrict__ out,
    int M)
{
    const int wave = threadIdx.x >> 6;
    const int lane = threadIdx.x & 63;
    const int r0 = (blockIdx.x * 4 + wave) * 16;
    if (r0 >= M) return;                    // no LDS / no syncthreads: safe
    const int mrow = lane & 15;
    const int quad = lane >> 4;
    const size_t rowA = (size_t)(r0 + mrow) * 128;

    floatx4 acc[NT];
#pragma unroll
    for (int t = 0; t < NT; ++t) acc[t] = (floatx4)(0.0f);

#pragma unroll
    for (int kk = 0; kk < 4; ++kk) {
        const int k = kk * 32 + quad * 8;
        bf16x8 aA = *(const bf16x8*)(inA + rowA + k);
        bf16x8 aS;
        if (DUAL) {
            if (SELF_F32) {
                const float* p = (const float*)inS + rowA + k;
                float4 lo = *(const float4*)p;
                float4 hi = *(const float4*)(p + 4);
                union { bf16x8 v; unsigned short u[8]; } c;
                c.u[0] = f2bf(lo.x); c.u[1] = f2bf(lo.y);
                c.u[2] = f2bf(lo.z); c.u[3] = f2bf(lo.w);
                c.u[4] = f2bf(hi.x); c.u[5] = f2bf(hi.y);
                c.u[6] = f2bf(hi.z); c.u[7] = f2bf(hi.w);
                aS = c.v;
            } else {
                aS = *(const bf16x8*)((const unsigned short*)inS + rowA + k);
            }
        }
#pragma unroll
        for (int t = 0; t < NT; ++t) {
            bf16x8 bl = *(const bf16x8*)(Wl + (size_t)(t * 16 + mrow) * 128 + k);
            acc[t] = __builtin_amdgcn_mfma_f32_16x16x32_bf16(aA, bl, acc[t], 0, 0, 0);
            if (DUAL) {
                bf16x8 br = *(const bf16x8*)(Wr + (size_t)(t * 16 + mrow) * 128 + k);
                acc[t] = __builtin_amdgcn_mfma_f32_16x16x32_bf16(aS, br, acc[t], 0, 0, 0);
            }
        }
    }

#pragma unroll
    for (int t = 0; t < NT; ++t) {
        float b = bias[t * 16 + mrow];
#pragma unroll
        for (int i = 0; i < 4; ++i) {
            float v = acc[t][i] + b;
            if (RELU) v = fmaxf(v, 0.0f);
            size_t o = (size_t)(r0 + quad * 4 + i) * (NT * 16) + t * 16 + mrow;
            if (OUT_BF16) ((unsigned short*)out)[o] = f2bf(v);
            else          ((float*)out)[o] = v;
        }
    }
}

// ---------------------------------------------------------------------------
extern "C" void kernel_launch(void* const* d_in, const int* in_sizes, int n_in,
                              void* d_out, int out_size, void* d_ws, size_t ws_size,
                              hipStream_t stream)
{
    const float* x   = (const float*)d_in[0];
    const int* ei    = (const int*)d_in[1];
    const float* W1l = (const float*)d_in[2];
    const float* b1l = (const float*)d_in[3];
    const float* W1r = (const float*)d_in[4];
    const float* W2l = (const float*)d_in[5];
    const float* b2l = (const float*)d_in[6];
    const float* W2r = (const float*)d_in[7];
    const float* W3  = (const float*)d_in[8];
    const float* b3  = (const float*)d_in[9];
    float* out = (float*)d_out;

    const int N = in_sizes[0] / 128;   // 50000
    const int E = in_sizes[1] / 2;     // 640000
    const int* src = ei;
    const int* dst = ei + E;

    // workspace layout (16B aligned):
    //   agg  : N*128 f32  (25.6 MB)  -- deg directly after: one zero pass
    //   deg  : N     f32  (0.2 MB)
    //   mean : N*128 bf16 (12.8 MB)
    //   h1   : N*128 bf16 (12.8 MB)
    //   h2   : N*128 bf16 (12.8 MB)
    //   wb*  : bf16 weights (W1l,W1r,W2l,W2r: 16384 ea; W3: 8192) ~147 KB
    char* ws = (char*)d_ws;
    float* agg = (float*)ws;
    float* deg = (float*)(ws + (size_t)N * 128 * 4);
    unsigned short* mean = (unsigned short*)(ws + (size_t)N * 129 * 4);
    unsigned short* h1  = mean + (size_t)N * 128;
    unsigned short* h2  = h1 + (size_t)N * 128;
    unsigned short* wb1l = h2 + (size_t)N * 128;
    unsigned short* wb1r = wb1l + 16384;
    unsigned short* wb2l = wb1r + 16384;
    unsigned short* wb2r = wb2l + 16384;
    unsigned short* wb3  = wb2r + 16384;

    const int tiles = (N + 15) / 16;
    const int gblk = (tiles + 3) / 4;
    const int sblk = (E + 1) / 2;            // 2 edges per 256-thread block
    const int mblk = (N * 32 + 255) / 256;

    // ---- weight conversion (tiny) ----
    hipLaunchKernelGGL(cvt_kernel, dim3(16), dim3(256), 0, stream, W1l, wb1l, 4096);
    hipLaunchKernelGGL(cvt_kernel, dim3(16), dim3(256), 0, stream, W1r, wb1r, 4096);
    hipLaunchKernelGGL(cvt_kernel, dim3(16), dim3(256), 0, stream, W2l, wb2l, 4096);
    hipLaunchKernelGGL(cvt_kernel, dim3(16), dim3(256), 0, stream, W2r, wb2r, 4096);
    hipLaunchKernelGGL(cvt_kernel, dim3(8),  dim3(256), 0, stream, W3,  wb3,  2048);

    // ---- layer 1 ----
    {
        int n4 = (N * 129) / 4;  // agg + deg contiguous
        hipLaunchKernelGGL(zero_kernel, dim3((n4 + 255) / 256), dim3(256), 0, stream,
                           agg, n4);
        hipLaunchKernelGGL((scatter_add_kernel<true, true>), dim3(sblk), dim3(256), 0,
                           stream, x, src, dst, agg, deg, E);
        hipLaunchKernelGGL(finalize_mean_kernel, dim3(mblk), dim3(256), 0, stream,
                           agg, deg, mean, N);
        hipLaunchKernelGGL((sage_gemm_kernel<8, true, true, true, true>), dim3(gblk),
                           dim3(256), 0, stream, mean, x, wb1l, wb1r, b1l, h1, N);
    }
    // ---- layer 2 ---- (deg unchanged; only agg re-zeroed)
    {
        int n4 = (N * 128) / 4;
        hipLaunchKernelGGL(zero_kernel, dim3((n4 + 255) / 256), dim3(256), 0, stream,
                           agg, n4);
        hipLaunchKernelGGL((scatter_add_kernel<false, false>), dim3(sblk), dim3(256), 0,
                           stream, h1, src, dst, agg, nullptr, E);
        hipLaunchKernelGGL(finalize_mean_kernel, dim3(mblk), dim3(256), 0, stream,
                           agg, deg, mean, N);
        hipLaunchKernelGGL((sage_gemm_kernel<8, true, false, true, true>), dim3(gblk),
                           dim3(256), 0, stream, mean, h1, wb2l, wb2r, b2l, h2, N);
    }
    // ---- output head ----
    hipLaunchKernelGGL((sage_gemm_kernel<4, false, false, false, false>), dim3(gblk),
                       dim3(256), 0, stream, h2, nullptr, wb3, nullptr, b3, out, N);
}

// Round 3
// 398.708 us; speedup vs baseline: 1.9598x; 1.9598x over previous
//
#include <hip/hip_runtime.h>

// ---------------------------------------------------------------------------
// GNN_6305011991202: 2-layer GraphSAGE (mean aggr) + linear head. fp32 I/O.
//   h1 = relu(mean1 @ W1_l^T + b1_l + x  @ W1_r^T)
//   h2 = relu(mean2 @ W2_l^T + b2_l + h1 @ W2_r^T)
//   out = h2 @ W3^T + b3          (out: [50000, 64] fp32)
// R3: atomics-free aggregation. Build CSR (counting sort by dst) once per
// launch, then gather-reduce per node (wave/node, 256B coalesced row reads,
// fp32 accum, fused mean+bf16 store). GEMMs on bf16 MFMA, fp32 accumulate.
// ---------------------------------------------------------------------------

typedef __bf16 bf16x8 __attribute__((ext_vector_type(8)));
typedef float floatx4 __attribute__((ext_vector_type(4)));

__device__ __forceinline__ float bf2f(unsigned short u) {
    union { unsigned int i; float f; } c;
    c.i = ((unsigned int)u) << 16;
    return c.f;
}
__device__ __forceinline__ unsigned short f2bf(float f) {
    union { float f; unsigned int i; } c;
    c.f = f;
    unsigned int i = c.i;
    unsigned int r = (i + 0x7fffu + ((i >> 16) & 1u)) >> 16;  // RNE
    return (unsigned short)r;
}

// ---------------------------------------------------------------------------
__global__ __launch_bounds__(256) void zero_kernel(float* __restrict__ p, int n4) {
    int i = blockIdx.x * 256 + threadIdx.x;
    if (i < n4) ((float4*)p)[i] = make_float4(0.f, 0.f, 0.f, 0.f);
}

// fp32 -> bf16 elementwise convert, 4 elems/thread
__global__ __launch_bounds__(256) void cvt_kernel(const float* __restrict__ in,
                                                  unsigned short* __restrict__ out,
                                                  int n4) {
    int i = blockIdx.x * 256 + threadIdx.x;
    if (i >= n4) return;
    float4 v = ((const float4*)in)[i];
    ushort4 o;
    o.x = f2bf(v.x); o.y = f2bf(v.y); o.z = f2bf(v.z); o.w = f2bf(v.w);
    ((ushort4*)out)[i] = o;
}

// ---------------------------------------------------------------------------
// CSR build step 1: degree histogram over dst
__global__ __launch_bounds__(256) void hist_kernel(const int* __restrict__ dst,
                                                   int* __restrict__ deg, int E) {
    int e = blockIdx.x * 256 + threadIdx.x;
    if (e < E) atomicAdd(deg + dst[e], 1);
}

// CSR build step 2: single-block exclusive scan (1024 thr, shfl wave-scan).
// Writes rowptr[0..N] and cursor[i] = rowptr[i].
__global__ __launch_bounds__(1024) void scan_kernel(const int* __restrict__ deg,
                                                    int* __restrict__ rowptr,
                                                    int* __restrict__ cursor, int N) {
    __shared__ int wsum[16];
    __shared__ int s_running;
    const int lane = threadIdx.x & 63;
    const int wave = threadIdx.x >> 6;
    if (threadIdx.x == 0) { s_running = 0; rowptr[0] = 0; }
    __syncthreads();
    for (int base = 0; base < N; base += 1024) {
        int i = base + threadIdx.x;
        int v = (i < N) ? deg[i] : 0;
        int incl = v;
#pragma unroll
        for (int off = 1; off < 64; off <<= 1) {
            int t = __shfl_up(incl, off, 64);
            if (lane >= off) incl += t;
        }
        if (lane == 63) wsum[wave] = incl;
        __syncthreads();
        if (wave == 0 && lane < 16) {
            int wv = wsum[lane];
            int wincl = wv;
#pragma unroll
            for (int off = 1; off < 16; off <<= 1) {
                int t = __shfl_up(wincl, off, 16);
                if (lane >= off) wincl += t;
            }
            wsum[lane] = wincl - wv;   // exclusive offset of this wave
        }
        __syncthreads();
        int myincl = incl + wsum[wave] + s_running;
        if (i < N) { rowptr[i + 1] = myincl; cursor[i] = myincl - v; }
        __syncthreads();               // all reads of s_running/wsum done
        if (threadIdx.x == 1023) s_running = myincl;
        __syncthreads();
    }
}

// CSR build step 3: scatter src ids into neighbor lists
__global__ __launch_bounds__(256) void fill_kernel(const int* __restrict__ src,
                                                   const int* __restrict__ dst,
                                                   int* __restrict__ cursor,
                                                   int* __restrict__ csr, int E) {
    int e = blockIdx.x * 256 + threadIdx.x;
    if (e >= E) return;
    int pos = atomicAdd(cursor + dst[e], 1);
    csr[pos] = src[e];
}

// ---------------------------------------------------------------------------
// Gather-reduce mean: one wave per node, lane holds 2 feature cols (bf16x2
// dword). Per 64 neighbors: one coalesced csr read, then shfl-broadcast each
// index and read the 256B bf16 row. Fused /deg + bf16 store.
__global__ __launch_bounds__(256) void gather_mean_kernel(
    const unsigned short* __restrict__ feat,   // [N,128] bf16
    const int* __restrict__ rowptr, const int* __restrict__ csr,
    unsigned short* __restrict__ mean, int N)
{
    const int wave = threadIdx.x >> 6;
    const int lane = threadIdx.x & 63;
    const int n = blockIdx.x * 4 + wave;
    if (n >= N) return;
    const int beg = rowptr[n], end = rowptr[n + 1];
    const int deg = end - beg;
    float acc0 = 0.f, acc1 = 0.f;
    for (int j0 = beg; j0 < end; j0 += 64) {
        int cnt = min(64, end - j0);
        int idx = (lane < cnt) ? csr[j0 + lane] : 0;
        for (int j = 0; j < cnt; ++j) {
            int s = __shfl(idx, j, 64);
            unsigned int p = *(const unsigned int*)(feat + (size_t)s * 128 + lane * 2);
            acc0 += bf2f((unsigned short)(p & 0xffffu));
            acc1 += bf2f((unsigned short)(p >> 16));
        }
    }
    float inv = (deg > 0) ? 1.0f / (float)deg : 0.0f;  // ref: 0/max(0,1)=0
    unsigned int o = (unsigned int)f2bf(acc0 * inv) |
                     ((unsigned int)f2bf(acc1 * inv) << 16);
    *(unsigned int*)(mean + (size_t)n * 128 + lane * 2) = o;
}

// ---------------------------------------------------------------------------
// Fused SAGE GEMM: out = [relu]( inA @ Wl^T + bias [+ inS @ Wr^T] )
// inA/inS: [M,128] bf16. Wl/Wr: bf16 [NT*16,128] (PyTorch [out_f,in_f] ->
// rows are B^T rows). bias fp32. out: bf16 (OUT_BF16) or fp32, [M, NT*16].
// One wave per 16 output rows; mfma_f32_16x16x32_bf16, fragment mapping
// (HW-verified m89/m91): A/B elem [m = lane&15][k = (lane>>4)*8 + j];
// C/D elem [row = (lane>>4)*4 + reg][col = lane&15].
template <int NT, bool DUAL, bool RELU, bool OUT_BF16>
__global__ __launch_bounds__(256) void sage_gemm_kernel(
    const unsigned short* __restrict__ inA,
    const unsigned short* __restrict__ inS,
    const unsigned short* __restrict__ Wl,
    const unsigned short* __restrict__ Wr,
    const float* __restrict__ bias,
    void* __restrict__ out,
    int M)
{
    const int wave = threadIdx.x >> 6;
    const int lane = threadIdx.x & 63;
    const int r0 = (blockIdx.x * 4 + wave) * 16;
    if (r0 >= M) return;                    // no LDS / no syncthreads: safe
    const int mrow = lane & 15;
    const int quad = lane >> 4;
    const size_t rowA = (size_t)(r0 + mrow) * 128;

    floatx4 acc[NT];
#pragma unroll
    for (int t = 0; t < NT; ++t) acc[t] = (floatx4)(0.0f);

#pragma unroll
    for (int kk = 0; kk < 4; ++kk) {
        const int k = kk * 32 + quad * 8;
        bf16x8 aA = *(const bf16x8*)(inA + rowA + k);
        bf16x8 aS;
        if (DUAL) aS = *(const bf16x8*)(inS + rowA + k);
#pragma unroll
        for (int t = 0; t < NT; ++t) {
            bf16x8 bl = *(const bf16x8*)(Wl + (size_t)(t * 16 + mrow) * 128 + k);
            acc[t] = __builtin_amdgcn_mfma_f32_16x16x32_bf16(aA, bl, acc[t], 0, 0, 0);
            if (DUAL) {
                bf16x8 br = *(const bf16x8*)(Wr + (size_t)(t * 16 + mrow) * 128 + k);
                acc[t] = __builtin_amdgcn_mfma_f32_16x16x32_bf16(aS, br, acc[t], 0, 0, 0);
            }
        }
    }

#pragma unroll
    for (int t = 0; t < NT; ++t) {
        float b = bias[t * 16 + mrow];
#pragma unroll
        for (int i = 0; i < 4; ++i) {
            float v = acc[t][i] + b;
            if (RELU) v = fmaxf(v, 0.0f);
            size_t o = (size_t)(r0 + quad * 4 + i) * (NT * 16) + t * 16 + mrow;
            if (OUT_BF16) ((unsigned short*)out)[o] = f2bf(v);
            else          ((float*)out)[o] = v;
        }
    }
}

// ---------------------------------------------------------------------------
extern "C" void kernel_launch(void* const* d_in, const int* in_sizes, int n_in,
                              void* d_out, int out_size, void* d_ws, size_t ws_size,
                              hipStream_t stream)
{
    const float* x   = (const float*)d_in[0];
    const int* ei    = (const int*)d_in[1];
    const float* W1l = (const float*)d_in[2];
    const float* b1l = (const float*)d_in[3];
    const float* W1r = (const float*)d_in[4];
    const float* W2l = (const float*)d_in[5];
    const float* b2l = (const float*)d_in[6];
    const float* W2r = (const float*)d_in[7];
    const float* W3  = (const float*)d_in[8];
    const float* b3  = (const float*)d_in[9];
    float* out = (float*)d_out;

    const int N = in_sizes[0] / 128;   // 50000
    const int E = in_sizes[1] / 2;     // 640000
    const int* src = ei;
    const int* dst = ei + E;

    // workspace layout (all offsets 16B aligned):
    //   deg_i  : N ints        rowptr : N+1 (padded to N+4) ints
    //   cursor : N ints        csr    : E ints (2.56 MB)
    //   xb/mean/h1/h2 : N*128 bf16 each (12.8 MB each)
    //   wb* : bf16 weights (~150 KB)
    int* deg_i  = (int*)d_ws;
    int* rowptr = deg_i + N;
    int* cursor = rowptr + N + 4;
    int* csr    = cursor + N;
    unsigned short* xb   = (unsigned short*)(csr + E);
    unsigned short* mean = xb + (size_t)N * 128;
    unsigned short* h1   = mean + (size_t)N * 128;
    unsigned short* h2   = h1 + (size_t)N * 128;
    unsigned short* wb1l = h2 + (size_t)N * 128;
    unsigned short* wb1r = wb1l + 16384;
    unsigned short* wb2l = wb1r + 16384;
    unsigned short* wb2r = wb2l + 16384;
    unsigned short* wb3  = wb2r + 16384;

    const int gblk = ((N + 15) / 16 + 3) / 4;   // gemm blocks (4 waves/block)
    const int nblk = (N + 3) / 4;               // gather blocks (4 nodes/block)
    const int eblk = (E + 255) / 256;

    // ---- weight + x conversion ----
    hipLaunchKernelGGL(cvt_kernel, dim3(16), dim3(256), 0, stream, W1l, wb1l, 4096);
    hipLaunchKernelGGL(cvt_kernel, dim3(16), dim3(256), 0, stream, W1r, wb1r, 4096);
    hipLaunchKernelGGL(cvt_kernel, dim3(16), dim3(256), 0, stream, W2l, wb2l, 4096);
    hipLaunchKernelGGL(cvt_kernel, dim3(16), dim3(256), 0, stream, W2r, wb2r, 4096);
    hipLaunchKernelGGL(cvt_kernel, dim3(8),  dim3(256), 0, stream, W3,  wb3,  2048);
    hipLaunchKernelGGL(cvt_kernel, dim3((N * 32 + 255) / 256), dim3(256), 0, stream,
                       x, xb, N * 32);

    // ---- CSR build (once; reused by both layers) ----
    hipLaunchKernelGGL(zero_kernel, dim3((N / 4 + 255) / 256), dim3(256), 0, stream,
                       (float*)deg_i, N / 4);
    hipLaunchKernelGGL(hist_kernel, dim3(eblk), dim3(256), 0, stream, dst, deg_i, E);
    hipLaunchKernelGGL(scan_kernel, dim3(1), dim3(1024), 0, stream,
                       deg_i, rowptr, cursor, N);
    hipLaunchKernelGGL(fill_kernel, dim3(eblk), dim3(256), 0, stream,
                       src, dst, cursor, csr, E);

    // ---- layer 1 ----
    hipLaunchKernelGGL(gather_mean_kernel, dim3(nblk), dim3(256), 0, stream,
                       xb, rowptr, csr, mean, N);
    hipLaunchKernelGGL((sage_gemm_kernel<8, true, true, true>), dim3(gblk), dim3(256),
                       0, stream, mean, xb, wb1l, wb1r, b1l, h1, N);
    // ---- layer 2 ----
    hipLaunchKernelGGL(gather_mean_kernel, dim3(nblk), dim3(256), 0, stream,
                       h1, rowptr, csr, mean, N);
    hipLaunchKernelGGL((sage_gemm_kernel<8, true, true, true>), dim3(gblk), dim3(256),
                       0, stream, mean, h1, wb2l, wb2r, b2l, h2, N);
    // ---- output head ----
    hipLaunchKernelGGL((sage_gemm_kernel<4, false, false, false>), dim3(gblk),
                       dim3(256), 0, stream, h2, nullptr, wb3, nullptr, b3, out, N);
}

// Round 4
// 311.390 us; speedup vs baseline: 2.5094x; 1.2804x over previous
//
#include <hip/hip_runtime.h>

// ---------------------------------------------------------------------------
// GNN_6305011991202: 2-layer GraphSAGE (mean aggr) + linear head. fp32 I/O.
//   h1 = relu(mean1 @ W1_l^T + b1_l + x  @ W1_r^T)
//   h2 = relu(mean2 @ W2_l^T + b2_l + h1 @ W2_r^T)
//   out = h2 @ W3^T + b3          (out: [50000, 64] fp32)
// R4: hierarchical 3-kernel CSR scan (was 50us single-block), fused
// convert+memset prologue (1 launch, was 7), 4x-unrolled gather inner loop.
// ---------------------------------------------------------------------------

typedef __bf16 bf16x8 __attribute__((ext_vector_type(8)));
typedef float floatx4 __attribute__((ext_vector_type(4)));

__device__ __forceinline__ float bf2f(unsigned short u) {
    union { unsigned int i; float f; } c;
    c.i = ((unsigned int)u) << 16;
    return c.f;
}
__device__ __forceinline__ unsigned short f2bf(float f) {
    union { float f; unsigned int i; } c;
    c.f = f;
    unsigned int i = c.i;
    unsigned int r = (i + 0x7fffu + ((i >> 16) & 1u)) >> 16;  // RNE
    return (unsigned short)r;
}
__device__ __forceinline__ ushort4 cvt4(float4 v) {
    ushort4 o;
    o.x = f2bf(v.x); o.y = f2bf(v.y); o.z = f2bf(v.z); o.w = f2bf(v.w);
    return o;
}

// ---------------------------------------------------------------------------
// Fused prologue: convert 5 weight mats (contiguous dst), convert x, zero deg.
// Segments (float4 units): [0,4096)W1l [4096,8192)W1r [8192,12288)W2l
// [12288,16384)W2r [16384,18432)W3 | [18432, 18432+NX4) x | then deg zero.
#define WSEG 18432
__global__ __launch_bounds__(256) void prologue_kernel(
    const float* __restrict__ W1l, const float* __restrict__ W1r,
    const float* __restrict__ W2l, const float* __restrict__ W2r,
    const float* __restrict__ W3,  const float* __restrict__ x,
    unsigned short* __restrict__ wb,   // 5 weight dsts contiguous
    unsigned short* __restrict__ xb,
    int* __restrict__ deg, int NX4, int ND4)
{
    int i = blockIdx.x * 256 + threadIdx.x;
    if (i < WSEG) {
        const float* s; int l;
        if (i < 8192)       { if (i < 4096) { s = W1l; l = i; }
                              else          { s = W1r; l = i - 4096; } }
        else if (i < 16384) { if (i < 12288){ s = W2l; l = i - 8192; }
                              else          { s = W2r; l = i - 12288; } }
        else                { s = W3; l = i - 16384; }
        ((ushort4*)wb)[i] = cvt4(((const float4*)s)[l]);
        return;
    }
    int j = i - WSEG;
    if (j < NX4) { ((ushort4*)xb)[j] = cvt4(((const float4*)x)[j]); return; }
    int k = j - NX4;
    if (k < ND4) ((int4*)deg)[k] = make_int4(0, 0, 0, 0);
}

// ---------------------------------------------------------------------------
// CSR build step 1: degree histogram over dst
__global__ __launch_bounds__(256) void hist_kernel(const int* __restrict__ dst,
                                                   int* __restrict__ deg, int E) {
    int e = blockIdx.x * 256 + threadIdx.x;
    if (e < E) atomicAdd(deg + dst[e], 1);
}

// CSR scan A: per-block sums (1024 elems/block)
__global__ __launch_bounds__(256) void scan_partial_kernel(
    const int* __restrict__ deg, int* __restrict__ partials, int N)
{
    __shared__ int ws[4];
    const int t = threadIdx.x, lane = t & 63, wave = t >> 6;
    const int i4 = blockIdx.x * 256 + t;
    const int n4 = (N + 3) / 4;
    int s = 0;
    if (i4 < n4) {
        int b = i4 * 4;
        if (b + 3 < N) {
            int4 v = ((const int4*)deg)[i4];
            s = v.x + v.y + v.z + v.w;
        } else {
            for (int q = 0; q < 4 && b + q < N; ++q) s += deg[b + q];
        }
    }
#pragma unroll
    for (int off = 32; off > 0; off >>= 1) s += __shfl_xor(s, off, 64);
    if (lane == 0) ws[wave] = s;
    __syncthreads();
    if (t == 0) partials[blockIdx.x] = ws[0] + ws[1] + ws[2] + ws[3];
}

// CSR scan B: single-wave exclusive scan of partials (P <= 64)
__global__ __launch_bounds__(64) void scan_partials_kernel(int* __restrict__ partials,
                                                           int P) {
    const int lane = threadIdx.x;
    int v = (lane < P) ? partials[lane] : 0;
    int incl = v;
#pragma unroll
    for (int off = 1; off < 64; off <<= 1) {
        int t = __shfl_up(incl, off, 64);
        if (lane >= off) incl += t;
    }
    if (lane < P) partials[lane] = incl - v;
}

// CSR scan C: re-scan locally + apply block offset; write rowptr & cursor
__global__ __launch_bounds__(256) void scan_apply_kernel(
    const int* __restrict__ deg, const int* __restrict__ partials,
    int* __restrict__ rowptr, int* __restrict__ cursor, int N)
{
    __shared__ int woff[4];
    const int t = threadIdx.x, lane = t & 63, wave = t >> 6;
    const int i4 = blockIdx.x * 256 + t;
    const int n4 = (N + 3) / 4;
    const int b = i4 * 4;
    int4 v = make_int4(0, 0, 0, 0);
    if (i4 < n4) {
        if (b + 3 < N) v = ((const int4*)deg)[i4];
        else {
            if (b + 0 < N) v.x = deg[b + 0];
            if (b + 1 < N) v.y = deg[b + 1];
            if (b + 2 < N) v.z = deg[b + 2];
        }
    }
    const int p1 = v.x, p2 = v.x + v.y, p3 = v.x + v.y + v.z;
    const int tsum = p3 + v.w;
    int incl = tsum;
#pragma unroll
    for (int off = 1; off < 64; off <<= 1) {
        int tt = __shfl_up(incl, off, 64);
        if (lane >= off) incl += tt;
    }
    const int texcl = incl - tsum;
    if (lane == 63) woff[wave] = incl;
    __syncthreads();
    int wo = 0;
#pragma unroll
    for (int w = 0; w < 4; ++w) if (w < wave) wo += woff[w];
    const int e = partials[blockIdx.x] + wo + texcl;
    if (blockIdx.x == 0 && t == 0) rowptr[0] = 0;
    if (b + 3 < N) {
        ((int4*)cursor)[i4] = make_int4(e, e + p1, e + p2, e + p3);
        rowptr[b + 1] = e + p1;
        rowptr[b + 2] = e + p2;
        rowptr[b + 3] = e + p3;
        rowptr[b + 4] = e + tsum;
    } else if (b < N) {
        if (b + 0 < N) { cursor[b + 0] = e;      rowptr[b + 1] = e + p1; }
        if (b + 1 < N) { cursor[b + 1] = e + p1; rowptr[b + 2] = e + p2; }
        if (b + 2 < N) { cursor[b + 2] = e + p2; rowptr[b + 3] = e + p3; }
    }
}

// CSR build: scatter src ids into neighbor lists
__global__ __launch_bounds__(256) void fill_kernel(const int* __restrict__ src,
                                                   const int* __restrict__ dst,
                                                   int* __restrict__ cursor,
                                                   int* __restrict__ csr, int E) {
    int e = blockIdx.x * 256 + threadIdx.x;
    if (e >= E) return;
    int pos = atomicAdd(cursor + dst[e], 1);
    csr[pos] = src[e];
}

// ---------------------------------------------------------------------------
// Gather-reduce mean: one wave per node, lane holds 2 feature cols (bf16x2
// dword). 4x unrolled neighbor loop (4 outstanding row loads). Fused /deg +
// bf16 store.
__global__ __launch_bounds__(256) void gather_mean_kernel(
    const unsigned short* __restrict__ feat,   // [N,128] bf16
    const int* __restrict__ rowptr, const int* __restrict__ csr,
    unsigned short* __restrict__ mean, int N)
{
    const int wave = threadIdx.x >> 6;
    const int lane = threadIdx.x & 63;
    const int n = blockIdx.x * 4 + wave;
    if (n >= N) return;
    const int beg = rowptr[n], end = rowptr[n + 1];
    const int deg = end - beg;
    float acc0 = 0.f, acc1 = 0.f;
    const unsigned short* fp = feat + lane * 2;
    for (int j0 = beg; j0 < end; j0 += 64) {
        int cnt = min(64, end - j0);
        int idx = (lane < cnt) ? csr[j0 + lane] : 0;
        int j = 0;
        for (; j + 4 <= cnt; j += 4) {
            int s0 = __shfl(idx, j + 0, 64);
            int s1 = __shfl(idx, j + 1, 64);
            int s2 = __shfl(idx, j + 2, 64);
            int s3 = __shfl(idx, j + 3, 64);
            unsigned int p0 = *(const unsigned int*)(fp + (size_t)s0 * 128);
            unsigned int p1 = *(const unsigned int*)(fp + (size_t)s1 * 128);
            unsigned int p2 = *(const unsigned int*)(fp + (size_t)s2 * 128);
            unsigned int p3 = *(const unsigned int*)(fp + (size_t)s3 * 128);
            acc0 += bf2f((unsigned short)(p0 & 0xffffu));
            acc1 += bf2f((unsigned short)(p0 >> 16));
            acc0 += bf2f((unsigned short)(p1 & 0xffffu));
            acc1 += bf2f((unsigned short)(p1 >> 16));
            acc0 += bf2f((unsigned short)(p2 & 0xffffu));
            acc1 += bf2f((unsigned short)(p2 >> 16));
            acc0 += bf2f((unsigned short)(p3 & 0xffffu));
            acc1 += bf2f((unsigned short)(p3 >> 16));
        }
        for (; j < cnt; ++j) {
            int s = __shfl(idx, j, 64);
            unsigned int p = *(const unsigned int*)(fp + (size_t)s * 128);
            acc0 += bf2f((unsigned short)(p & 0xffffu));
            acc1 += bf2f((unsigned short)(p >> 16));
        }
    }
    float inv = (deg > 0) ? 1.0f / (float)deg : 0.0f;  // ref: 0/max(0,1)=0
    unsigned int o = (unsigned int)f2bf(acc0 * inv) |
                     ((unsigned int)f2bf(acc1 * inv) << 16);
    *(unsigned int*)(mean + (size_t)n * 128 + lane * 2) = o;
}

// ---------------------------------------------------------------------------
// Fused SAGE GEMM: out = [relu]( inA @ Wl^T + bias [+ inS @ Wr^T] )
// inA/inS: [M,128] bf16. Wl/Wr: bf16 [NT*16,128] (PyTorch [out_f,in_f] ->
// rows are B^T rows). bias fp32. out: bf16 (OUT_BF16) or fp32, [M, NT*16].
// One wave per 16 output rows; mfma_f32_16x16x32_bf16, fragment mapping
// (HW-verified m89/m91): A/B elem [m = lane&15][k = (lane>>4)*8 + j];
// C/D elem [row = (lane>>4)*4 + reg][col = lane&15].
template <int NT, bool DUAL, bool RELU, bool OUT_BF16>
__global__ __launch_bounds__(256) void sage_gemm_kernel(
    const unsigned short* __restrict__ inA,
    const unsigned short* __restrict__ inS,
    const unsigned short* __restrict__ Wl,
    const unsigned short* __restrict__ Wr,
    const float* __restrict__ bias,
    void* __restrict__ out,
    int M)
{
    const int wave = threadIdx.x >> 6;
    const int lane = threadIdx.x & 63;
    const int r0 = (blockIdx.x * 4 + wave) * 16;
    if (r0 >= M) return;                    // no LDS / no syncthreads: safe
    const int mrow = lane & 15;
    const int quad = lane >> 4;
    const size_t rowA = (size_t)(r0 + mrow) * 128;

    floatx4 acc[NT];
#pragma unroll
    for (int t = 0; t < NT; ++t) acc[t] = (floatx4)(0.0f);

#pragma unroll
    for (int kk = 0; kk < 4; ++kk) {
        const int k = kk * 32 + quad * 8;
        bf16x8 aA = *(const bf16x8*)(inA + rowA + k);
        bf16x8 aS;
        if (DUAL) aS = *(const bf16x8*)(inS + rowA + k);
#pragma unroll
        for (int t = 0; t < NT; ++t) {
            bf16x8 bl = *(const bf16x8*)(Wl + (size_t)(t * 16 + mrow) * 128 + k);
            acc[t] = __builtin_amdgcn_mfma_f32_16x16x32_bf16(aA, bl, acc[t], 0, 0, 0);
            if (DUAL) {
                bf16x8 br = *(const bf16x8*)(Wr + (size_t)(t * 16 + mrow) * 128 + k);
                acc[t] = __builtin_amdgcn_mfma_f32_16x16x32_bf16(aS, br, acc[t], 0, 0, 0);
            }
        }
    }

#pragma unroll
    for (int t = 0; t < NT; ++t) {
        float b = bias[t * 16 + mrow];
#pragma unroll
        for (int i = 0; i < 4; ++i) {
            float v = acc[t][i] + b;
            if (RELU) v = fmaxf(v, 0.0f);
            size_t o = (size_t)(r0 + quad * 4 + i) * (NT * 16) + t * 16 + mrow;
            if (OUT_BF16) ((unsigned short*)out)[o] = f2bf(v);
            else          ((float*)out)[o] = v;
        }
    }
}

// ---------------------------------------------------------------------------
extern "C" void kernel_launch(void* const* d_in, const int* in_sizes, int n_in,
                              void* d_out, int out_size, void* d_ws, size_t ws_size,
                              hipStream_t stream)
{
    const float* x   = (const float*)d_in[0];
    const int* ei    = (const int*)d_in[1];
    const float* W1l = (const float*)d_in[2];
    const float* b1l = (const float*)d_in[3];
    const float* W1r = (const float*)d_in[4];
    const float* W2l = (const float*)d_in[5];
    const float* b2l = (const float*)d_in[6];
    const float* W2r = (const float*)d_in[7];
    const float* W3  = (const float*)d_in[8];
    const float* b3  = (const float*)d_in[9];
    float* out = (float*)d_out;

    const int N = in_sizes[0] / 128;   // 50000
    const int E = in_sizes[1] / 2;     // 640000
    const int* src = ei;
    const int* dst = ei + E;

    // workspace layout (all offsets 16B aligned):
    //   deg_i  : N ints (pad to x4)   partials: 64 ints
    //   rowptr : N+4 ints             cursor  : N ints
    //   csr    : E ints (2.56 MB)
    //   xb/mean/h1/h2 : N*128 bf16 each (12.8 MB each)
    //   wb : 5 bf16 weight mats contiguous (~150 KB)
    const int n4 = (N + 3) / 4;
    int* deg_i    = (int*)d_ws;
    int* partials = deg_i + n4 * 4;
    int* rowptr   = partials + 64;
    int* cursor   = rowptr + N + 4;
    int* csr      = cursor + n4 * 4;
    unsigned short* xb   = (unsigned short*)(csr + E);
    unsigned short* mean = xb + (size_t)N * 128;
    unsigned short* h1   = mean + (size_t)N * 128;
    unsigned short* h2   = h1 + (size_t)N * 128;
    unsigned short* wb1l = h2 + (size_t)N * 128;
    unsigned short* wb1r = wb1l + 16384;
    unsigned short* wb2l = wb1r + 16384;
    unsigned short* wb2r = wb2l + 16384;
    unsigned short* wb3  = wb2r + 16384;

    const int gblk = ((N + 15) / 16 + 3) / 4;   // gemm blocks (4 waves/block)
    const int nblk = (N + 3) / 4;               // gather blocks (4 nodes/block)
    const int eblk = (E + 255) / 256;
    const int NX4  = N * 32;                    // x in float4 units
    const int P    = (n4 + 255) / 256;          // scan blocks (<=64 for N<=65536)

    // ---- fused prologue: weight cvt + x cvt + deg zero (1 launch) ----
    {
        int total = WSEG + NX4 + n4;
        hipLaunchKernelGGL(prologue_kernel, dim3((total + 255) / 256), dim3(256), 0,
                           stream, W1l, W1r, W2l, W2r, W3, x, wb1l, xb, deg_i,
                           NX4, n4);
    }

    // ---- CSR build (once; reused by both layers) ----
    hipLaunchKernelGGL(hist_kernel, dim3(eblk), dim3(256), 0, stream, dst, deg_i, E);
    hipLaunchKernelGGL(scan_partial_kernel, dim3(P), dim3(256), 0, stream,
                       deg_i, partials, N);
    hipLaunchKernelGGL(scan_partials_kernel, dim3(1), dim3(64), 0, stream,
                       partials, P);
    hipLaunchKernelGGL(scan_apply_kernel, dim3(P), dim3(256), 0, stream,
                       deg_i, partials, rowptr, cursor, N);
    hipLaunchKernelGGL(fill_kernel, dim3(eblk), dim3(256), 0, stream,
                       src, dst, cursor, csr, E);

    // ---- layer 1 ----
    hipLaunchKernelGGL(gather_mean_kernel, dim3(nblk), dim3(256), 0, stream,
                       xb, rowptr, csr, mean, N);
    hipLaunchKernelGGL((sage_gemm_kernel<8, true, true, true>), dim3(gblk), dim3(256),
                       0, stream, mean, xb, wb1l, wb1r, b1l, h1, N);
    // ---- layer 2 ----
    hipLaunchKernelGGL(gather_mean_kernel, dim3(nblk), dim3(256), 0, stream,
                       h1, rowptr, csr, mean, N);
    hipLaunchKernelGGL((sage_gemm_kernel<8, true, true, true>), dim3(gblk), dim3(256),
                       0, stream, mean, h1, wb2l, wb2r, b2l, h2, N);
    // ---- output head ----
    hipLaunchKernelGGL((sage_gemm_kernel<4, false, false, false>), dim3(gblk),
                       dim3(256), 0, stream, h2, nullptr, wb3, nullptr, b3, out, N);
}

// Round 5
// 306.053 us; speedup vs baseline: 2.5532x; 1.0174x over previous
//
#include <hip/hip_runtime.h>

// ---------------------------------------------------------------------------
// GNN_6305011991202: 2-layer GraphSAGE (mean aggr) + linear head. fp32 I/O.
//   h1 = relu(mean1 @ W1_l^T + b1_l + x  @ W1_r^T)
//   h2 = relu(mean2 @ W2_l^T + b2_l + h1 @ W2_r^T)
//   out = h2 @ W3^T + b3          (out: [50000, 64] fp32)
// R5: gather v2 (2 neighbors per wave-load via half-wave split, 8-deep ILP),
// scan step B folded into step C (10 launches total).
// ---------------------------------------------------------------------------

typedef __bf16 bf16x8 __attribute__((ext_vector_type(8)));
typedef float floatx4 __attribute__((ext_vector_type(4)));

__device__ __forceinline__ float bf2f(unsigned int u) {
    union { unsigned int i; float f; } c;
    c.i = u << 16;
    return c.f;
}
__device__ __forceinline__ unsigned short f2bf(float f) {
    union { float f; unsigned int i; } c;
    c.f = f;
    unsigned int i = c.i;
    unsigned int r = (i + 0x7fffu + ((i >> 16) & 1u)) >> 16;  // RNE
    return (unsigned short)r;
}
__device__ __forceinline__ ushort4 cvt4(float4 v) {
    ushort4 o;
    o.x = f2bf(v.x); o.y = f2bf(v.y); o.z = f2bf(v.z); o.w = f2bf(v.w);
    return o;
}

// ---------------------------------------------------------------------------
// Fused prologue: convert 5 weight mats (contiguous dst), convert x, zero deg.
// Segments (float4 units): [0,18432) weights | [.., +NX4) x | then deg zero.
#define WSEG 18432
__global__ __launch_bounds__(256) void prologue_kernel(
    const float* __restrict__ W1l, const float* __restrict__ W1r,
    const float* __restrict__ W2l, const float* __restrict__ W2r,
    const float* __restrict__ W3,  const float* __restrict__ x,
    unsigned short* __restrict__ wb,   // 5 weight dsts contiguous
    unsigned short* __restrict__ xb,
    int* __restrict__ deg, int NX4, int ND4)
{
    int i = blockIdx.x * 256 + threadIdx.x;
    if (i < WSEG) {
        const float* s; int l;
        if (i < 8192)       { if (i < 4096) { s = W1l; l = i; }
                              else          { s = W1r; l = i - 4096; } }
        else if (i < 16384) { if (i < 12288){ s = W2l; l = i - 8192; }
                              else          { s = W2r; l = i - 12288; } }
        else                { s = W3; l = i - 16384; }
        ((ushort4*)wb)[i] = cvt4(((const float4*)s)[l]);
        return;
    }
    int j = i - WSEG;
    if (j < NX4) { ((ushort4*)xb)[j] = cvt4(((const float4*)x)[j]); return; }
    int k = j - NX4;
    if (k < ND4) ((int4*)deg)[k] = make_int4(0, 0, 0, 0);
}

// ---------------------------------------------------------------------------
// CSR build step 1: degree histogram over dst
__global__ __launch_bounds__(256) void hist_kernel(const int* __restrict__ dst,
                                                   int* __restrict__ deg, int E) {
    int e = blockIdx.x * 256 + threadIdx.x;
    if (e < E) atomicAdd(deg + dst[e], 1);
}

// CSR scan A: per-block sums (1024 elems/block)
__global__ __launch_bounds__(256) void scan_partial_kernel(
    const int* __restrict__ deg, int* __restrict__ partials, int N)
{
    __shared__ int ws[4];
    const int t = threadIdx.x, lane = t & 63, wave = t >> 6;
    const int i4 = blockIdx.x * 256 + t;
    const int n4 = (N + 3) / 4;
    int s = 0;
    if (i4 < n4) {
        int b = i4 * 4;
        if (b + 3 < N) {
            int4 v = ((const int4*)deg)[i4];
            s = v.x + v.y + v.z + v.w;
        } else {
            for (int q = 0; q < 4 && b + q < N; ++q) s += deg[b + q];
        }
    }
#pragma unroll
    for (int off = 32; off > 0; off >>= 1) s += __shfl_xor(s, off, 64);
    if (lane == 0) ws[wave] = s;
    __syncthreads();
    if (t == 0) partials[blockIdx.x] = ws[0] + ws[1] + ws[2] + ws[3];
}

// CSR scan B+C merged: each block redundantly reduces partials[< blockIdx]
// (P <= 64), re-scans its 1024 elems, writes rowptr & cursor.
__global__ __launch_bounds__(256) void scan_apply_kernel(
    const int* __restrict__ deg, const int* __restrict__ partials,
    int* __restrict__ rowptr, int* __restrict__ cursor, int N, int P)
{
    __shared__ int woff[4];
    __shared__ int s_base;
    const int t = threadIdx.x, lane = t & 63, wave = t >> 6;
    const int i4 = blockIdx.x * 256 + t;
    const int n4 = (N + 3) / 4;
    const int b = i4 * 4;

    if (wave == 0) {          // exclusive sum of block partials below us
        int v = (lane < P && lane < (int)blockIdx.x) ? partials[lane] : 0;
#pragma unroll
        for (int off = 32; off > 0; off >>= 1) v += __shfl_xor(v, off, 64);
        if (lane == 0) s_base = v;
    }

    int4 v = make_int4(0, 0, 0, 0);
    if (i4 < n4) {
        if (b + 3 < N) v = ((const int4*)deg)[i4];
        else {
            if (b + 0 < N) v.x = deg[b + 0];
            if (b + 1 < N) v.y = deg[b + 1];
            if (b + 2 < N) v.z = deg[b + 2];
        }
    }
    const int p1 = v.x, p2 = v.x + v.y, p3 = v.x + v.y + v.z;
    const int tsum = p3 + v.w;
    int incl = tsum;
#pragma unroll
    for (int off = 1; off < 64; off <<= 1) {
        int tt = __shfl_up(incl, off, 64);
        if (lane >= off) incl += tt;
    }
    const int texcl = incl - tsum;
    if (lane == 63) woff[wave] = incl;
    __syncthreads();
    int wo = 0;
#pragma unroll
    for (int w = 0; w < 4; ++w) if (w < wave) wo += woff[w];
    const int e = s_base + wo + texcl;
    if (blockIdx.x == 0 && t == 0) rowptr[0] = 0;
    if (b + 3 < N) {
        ((int4*)cursor)[i4] = make_int4(e, e + p1, e + p2, e + p3);
        rowptr[b + 1] = e + p1;
        rowptr[b + 2] = e + p2;
        rowptr[b + 3] = e + p3;
        rowptr[b + 4] = e + tsum;
    } else if (b < N) {
        if (b + 0 < N) { cursor[b + 0] = e;      rowptr[b + 1] = e + p1; }
        if (b + 1 < N) { cursor[b + 1] = e + p1; rowptr[b + 2] = e + p2; }
        if (b + 2 < N) { cursor[b + 2] = e + p2; rowptr[b + 3] = e + p3; }
    }
}

// CSR build: scatter src ids into neighbor lists
__global__ __launch_bounds__(256) void fill_kernel(const int* __restrict__ src,
                                                   const int* __restrict__ dst,
                                                   int* __restrict__ cursor,
                                                   int* __restrict__ csr, int E) {
    int e = blockIdx.x * 256 + threadIdx.x;
    if (e >= E) return;
    int pos = atomicAdd(cursor + dst[e], 1);
    csr[pos] = src[e];
}

// ---------------------------------------------------------------------------
// Gather-reduce mean v2: one wave per node. Half-wave split: lanes 0-31 hold
// 4 cols (8B) of even neighbors, lanes 32-63 of odd neighbors -> one dwordx2
// load moves 2 neighbor rows (512B). 4 loads (8 neighbors) in flight.
// Epilogue: shfl_xor(32) cross-half reduce, half-wave bf16 store.
__global__ __launch_bounds__(256) void gather_mean_kernel(
    const unsigned short* __restrict__ feat,   // [N,128] bf16
    const int* __restrict__ rowptr, const int* __restrict__ csr,
    unsigned short* __restrict__ mean, int N)
{
    const int wave = threadIdx.x >> 6;
    const int lane = threadIdx.x & 63;
    const int half = lane >> 5;
    const int n = blockIdx.x * 4 + wave;
    if (n >= N) return;
    const int beg = rowptr[n], end = rowptr[n + 1];
    const int deg = end - beg;
    float a0 = 0.f, a1 = 0.f, a2 = 0.f, a3 = 0.f;
    const unsigned short* fp = feat + (lane & 31) * 4;   // 4 cols/lane

#define ACC4(P) do {                                \
        a0 += bf2f((P).x << 16 >> 16 ? ((P).x & 0xffffu) : 0u); } while(0)
#undef ACC4

    for (int j0 = beg; j0 < end; j0 += 64) {
        int cnt = min(64, end - j0);
        int idx = (lane < cnt) ? csr[j0 + lane] : 0;
        int pairs = cnt >> 1;
        int m = 0;
        for (; m + 4 <= pairs; m += 4) {
            int s0 = __shfl(idx, 2 * m + 0 + half, 64);
            int s1 = __shfl(idx, 2 * m + 2 + half, 64);
            int s2 = __shfl(idx, 2 * m + 4 + half, 64);
            int s3 = __shfl(idx, 2 * m + 6 + half, 64);
            uint2 p0 = *(const uint2*)(fp + (size_t)s0 * 128);
            uint2 p1 = *(const uint2*)(fp + (size_t)s1 * 128);
            uint2 p2 = *(const uint2*)(fp + (size_t)s2 * 128);
            uint2 p3 = *(const uint2*)(fp + (size_t)s3 * 128);
            a0 += bf2f(p0.x & 0xffffu); a1 += bf2f(p0.x >> 16);
            a2 += bf2f(p0.y & 0xffffu); a3 += bf2f(p0.y >> 16);
            a0 += bf2f(p1.x & 0xffffu); a1 += bf2f(p1.x >> 16);
            a2 += bf2f(p1.y & 0xffffu); a3 += bf2f(p1.y >> 16);
            a0 += bf2f(p2.x & 0xffffu); a1 += bf2f(p2.x >> 16);
            a2 += bf2f(p2.y & 0xffffu); a3 += bf2f(p2.y >> 16);
            a0 += bf2f(p3.x & 0xffffu); a1 += bf2f(p3.x >> 16);
            a2 += bf2f(p3.y & 0xffffu); a3 += bf2f(p3.y >> 16);
        }
        for (; m < pairs; ++m) {
            int s = __shfl(idx, 2 * m + half, 64);
            uint2 p = *(const uint2*)(fp + (size_t)s * 128);
            a0 += bf2f(p.x & 0xffffu); a1 += bf2f(p.x >> 16);
            a2 += bf2f(p.y & 0xffffu); a3 += bf2f(p.y >> 16);
        }
        if (cnt & 1) {                       // odd tail: half 0 only
            int s = __shfl(idx, cnt - 1, 64);
            uint2 p = *(const uint2*)(fp + (size_t)s * 128);
            if (half == 0) {
                a0 += bf2f(p.x & 0xffffu); a1 += bf2f(p.x >> 16);
                a2 += bf2f(p.y & 0xffffu); a3 += bf2f(p.y >> 16);
            }
        }
    }
    a0 += __shfl_xor(a0, 32, 64);
    a1 += __shfl_xor(a1, 32, 64);
    a2 += __shfl_xor(a2, 32, 64);
    a3 += __shfl_xor(a3, 32, 64);
    if (half == 0) {
        float inv = (deg > 0) ? 1.0f / (float)deg : 0.0f;  // ref: 0/max(0,1)=0
        uint2 o;
        o.x = (unsigned)f2bf(a0 * inv) | ((unsigned)f2bf(a1 * inv) << 16);
        o.y = (unsigned)f2bf(a2 * inv) | ((unsigned)f2bf(a3 * inv) << 16);
        *(uint2*)(mean + (size_t)n * 128 + (lane & 31) * 4) = o;
    }
}

// ---------------------------------------------------------------------------
// Fused SAGE GEMM: out = [relu]( inA @ Wl^T + bias [+ inS @ Wr^T] )
// inA/inS: [M,128] bf16. Wl/Wr: bf16 [NT*16,128]. bias fp32. out bf16/fp32.
// One wave per 16 output rows; mfma_f32_16x16x32_bf16 (HW-verified layout):
// A/B elem [m = lane&15][k = (lane>>4)*8 + j]; C/D [row=(lane>>4)*4+reg][col=lane&15].
template <int NT, bool DUAL, bool RELU, bool OUT_BF16>
__global__ __launch_bounds__(256) void sage_gemm_kernel(
    const unsigned short* __restrict__ inA,
    const unsigned short* __restrict__ inS,
    const unsigned short* __restrict__ Wl,
    const unsigned short* __restrict__ Wr,
    const float* __restrict__ bias,
    void* __restrict__ out,
    int M)
{
    const int wave = threadIdx.x >> 6;
    const int lane = threadIdx.x & 63;
    const int r0 = (blockIdx.x * 4 + wave) * 16;
    if (r0 >= M) return;                    // no LDS / no syncthreads: safe
    const int mrow = lane & 15;
    const int quad = lane >> 4;
    const size_t rowA = (size_t)(r0 + mrow) * 128;

    floatx4 acc[NT];
#pragma unroll
    for (int t = 0; t < NT; ++t) acc[t] = (floatx4)(0.0f);

#pragma unroll
    for (int kk = 0; kk < 4; ++kk) {
        const int k = kk * 32 + quad * 8;
        bf16x8 aA = *(const bf16x8*)(inA + rowA + k);
        bf16x8 aS;
        if (DUAL) aS = *(const bf16x8*)(inS + rowA + k);
#pragma unroll
        for (int t = 0; t < NT; ++t) {
            bf16x8 bl = *(const bf16x8*)(Wl + (size_t)(t * 16 + mrow) * 128 + k);
            acc[t] = __builtin_amdgcn_mfma_f32_16x16x32_bf16(aA, bl, acc[t], 0, 0, 0);
            if (DUAL) {
                bf16x8 br = *(const bf16x8*)(Wr + (size_t)(t * 16 + mrow) * 128 + k);
                acc[t] = __builtin_amdgcn_mfma_f32_16x16x32_bf16(aS, br, acc[t], 0, 0, 0);
            }
        }
    }

#pragma unroll
    for (int t = 0; t < NT; ++t) {
        float b = bias[t * 16 + mrow];
#pragma unroll
        for (int i = 0; i < 4; ++i) {
            float v = acc[t][i] + b;
            if (RELU) v = fmaxf(v, 0.0f);
            size_t o = (size_t)(r0 + quad * 4 + i) * (NT * 16) + t * 16 + mrow;
            if (OUT_BF16) ((unsigned short*)out)[o] = f2bf(v);
            else          ((float*)out)[o] = v;
        }
    }
}

// ---------------------------------------------------------------------------
extern "C" void kernel_launch(void* const* d_in, const int* in_sizes, int n_in,
                              void* d_out, int out_size, void* d_ws, size_t ws_size,
                              hipStream_t stream)
{
    const float* x   = (const float*)d_in[0];
    const int* ei    = (const int*)d_in[1];
    const float* W1l = (const float*)d_in[2];
    const float* b1l = (const float*)d_in[3];
    const float* W1r = (const float*)d_in[4];
    const float* W2l = (const float*)d_in[5];
    const float* b2l = (const float*)d_in[6];
    const float* W2r = (const float*)d_in[7];
    const float* W3  = (const float*)d_in[8];
    const float* b3  = (const float*)d_in[9];
    float* out = (float*)d_out;

    const int N = in_sizes[0] / 128;   // 50000
    const int E = in_sizes[1] / 2;     // 640000
    const int* src = ei;
    const int* dst = ei + E;

    // workspace layout (all offsets 16B aligned):
    //   deg_i : N ints (pad x4)  partials: 64 ints
    //   rowptr: N+4 ints         cursor  : N ints
    //   csr   : E ints           xb/mean/h1/h2: N*128 bf16 each
    //   wb    : 5 bf16 weight mats contiguous
    const int n4 = (N + 3) / 4;
    int* deg_i    = (int*)d_ws;
    int* partials = deg_i + n4 * 4;
    int* rowptr   = partials + 64;
    int* cursor   = rowptr + N + 4;
    int* csr      = cursor + n4 * 4;
    unsigned short* xb   = (unsigned short*)(csr + E);
    unsigned short* mean = xb + (size_t)N * 128;
    unsigned short* h1   = mean + (size_t)N * 128;
    unsigned short* h2   = h1 + (size_t)N * 128;
    unsigned short* wb1l = h2 + (size_t)N * 128;
    unsigned short* wb1r = wb1l + 16384;
    unsigned short* wb2l = wb1r + 16384;
    unsigned short* wb2r = wb2l + 16384;
    unsigned short* wb3  = wb2r + 16384;

    const int gblk = ((N + 15) / 16 + 3) / 4;   // gemm blocks (4 waves/block)
    const int nblk = (N + 3) / 4;               // gather blocks (4 nodes/block)
    const int eblk = (E + 255) / 256;
    const int NX4  = N * 32;                    // x in float4 units
    const int P    = (n4 + 255) / 256;          // scan blocks (<=64 for N<=65536)

    // ---- fused prologue: weight cvt + x cvt + deg zero (1 launch) ----
    {
        int total = WSEG + NX4 + n4;
        hipLaunchKernelGGL(prologue_kernel, dim3((total + 255) / 256), dim3(256), 0,
                           stream, W1l, W1r, W2l, W2r, W3, x, wb1l, xb, deg_i,
                           NX4, n4);
    }

    // ---- CSR build (once; reused by both layers) ----
    hipLaunchKernelGGL(hist_kernel, dim3(eblk), dim3(256), 0, stream, dst, deg_i, E);
    hipLaunchKernelGGL(scan_partial_kernel, dim3(P), dim3(256), 0, stream,
                       deg_i, partials, N);
    hipLaunchKernelGGL(scan_apply_kernel, dim3(P), dim3(256), 0, stream,
                       deg_i, partials, rowptr, cursor, N, P);
    hipLaunchKernelGGL(fill_kernel, dim3(eblk), dim3(256), 0, stream,
                       src, dst, cursor, csr, E);

    // ---- layer 1 ----
    hipLaunchKernelGGL(gather_mean_kernel, dim3(nblk), dim3(256), 0, stream,
                       xb, rowptr, csr, mean, N);
    hipLaunchKernelGGL((sage_gemm_kernel<8, true, true, true>), dim3(gblk), dim3(256),
                       0, stream, mean, xb, wb1l, wb1r, b1l, h1, N);
    // ---- layer 2 ----
    hipLaunchKernelGGL(gather_mean_kernel, dim3(nblk), dim3(256), 0, stream,
                       h1, rowptr, csr, mean, N);
    hipLaunchKernelGGL((sage_gemm_kernel<8, true, true, true>), dim3(gblk), dim3(256),
                       0, stream, mean, h1, wb2l, wb2r, b2l, h2, N);
    // ---- output head ----
    hipLaunchKernelGGL((sage_gemm_kernel<4, false, false, false>), dim3(gblk),
                       dim3(256), 0, stream, h2, nullptr, wb3, nullptr, b3, out, N);
}